// Round 6
// baseline (261.023 us; speedup 1.0000x reference)
//
#include <hip/hip_runtime.h>
#include <cstddef>
#include <cstdint>

#define BSZ   4
#define SEQ   4096
#define DIN   1024
#define HDIM  1024
#define MTOT  (BSZ * SEQ)            // 16384 rows
#define NELE  ((size_t)MTOT * HDIM)
#define NX    ((size_t)MTOT * DIN)
#define NW    ((size_t)HDIM * DIN)
#define NCH   256                    // scan chunks (CL=16)
#define CL    (SEQ / NCH)

#define X4 (NX / 4)
#define W4 (NW / 4)

// GEMM tile geometry: 256x128 tile, BK=64, 2 tiles (m, m+8192) per block
#define GBM 256
#define GBN 128
#define GBK 64
#define NKT (DIN / GBK)              // 16 K-tiles
#define AOFF ((size_t)8192 * 2048)   // byte offset to second-rep A panel

using bf16x8 = __attribute__((ext_vector_type(8))) __bf16;
using f32x4  = __attribute__((ext_vector_type(4))) float;

// ---------- bf16 bit helpers ----------
__device__ __forceinline__ float bf2f(unsigned int u16bits) {
    union { unsigned int i; float f; } v;
    v.i = u16bits << 16;
    return v.f;
}
__device__ __forceinline__ unsigned int pk2(float a, float b) {  // (lo=a, hi=b)
    union { float f; unsigned int i; } ua, ub; ua.f = a; ub.f = b;
    return ((ua.i + 0x8000u) >> 16) | ((ub.i + 0x8000u) & 0xffff0000u);
}

// async 16B global -> LDS (wave-uniform LDS base; HW adds lane*16)
__device__ __forceinline__ void gload16(const void* g, void* l) {
    __builtin_amdgcn_global_load_lds(
        (const __attribute__((address_space(1))) unsigned int*)g,
        (__attribute__((address_space(3))) unsigned int*)l, 16, 0, 0);
}

// ---------- fp32 -> bf16 pre-convert (x, Wz, Wh), 8 floats/thread ----------
__global__ __launch_bounds__(256) void cvt_bf16(
    const float* __restrict__ x, const float* __restrict__ wz,
    const float* __restrict__ wh, unsigned short* __restrict__ xb,
    unsigned short* __restrict__ zb, unsigned short* __restrict__ hb)
{
    const size_t i = (size_t)blockIdx.x * 256 + threadIdx.x;   // uint4-pair index
    const float4* s; uint4* d; size_t off;
    const size_t xh = X4 / 2, wh4 = W4 / 2;
    if (i < xh)            { s = (const float4*)x;  d = (uint4*)xb; off = i; }
    else if (i < xh + wh4) { s = (const float4*)wz; d = (uint4*)zb; off = i - xh; }
    else                   { s = (const float4*)wh; d = (uint4*)hb; off = i - xh - wh4; }
    const float4 v0 = s[2 * off];
    const float4 v1 = s[2 * off + 1];
    uint4 r;
    r.x = pk2(v0.x, v0.y); r.y = pk2(v0.z, v0.w);
    r.z = pk2(v1.x, v1.y); r.w = pk2(v1.z, v1.w);
    d[off] = r;
}

// ---------- helper macros for the pipelined GEMM ----------
#define SBAR  __builtin_amdgcn_sched_barrier(0)
#define PRIO1 __builtin_amdgcn_s_setprio(1)
#define PRIO0 __builtin_amdgcn_s_setprio(0)

#define MFMA1(acc, va, vb) \
    acc = __builtin_amdgcn_mfma_f32_16x16x32_bf16(va, vb, acc, 0, 0, 0)

// 32 MFMA for mt-pair P, kk-OUTER: first 16 independent, each dependent
// accumulate 16 issues behind its producer (was 2 -> latency stalls).
#define MFMA_PAIR(P, AV, S)                                                    \
    _Pragma("unroll")                                                          \
    for (int kk_ = 0; kk_ < 2; ++kk_) {                                        \
        _Pragma("unroll")                                                      \
        for (int i_ = 0; i_ < 2; ++i_) {                                       \
            _Pragma("unroll")                                                  \
            for (int nt_ = 0; nt_ < 2; ++nt_) {                                \
                MFMA1(accz[2*(P)+i_][nt_], AV[i_][kk_], Bz[S][nt_][kk_]);      \
                MFMA1(acch[2*(P)+i_][nt_], AV[i_][kk_], Bh[S][nt_][kk_]);      \
            }                                                                  \
        }                                                                      \
    }

// read A-frag pair MTP (rows 2*MTP, 2*MTP+1) from buffer B into set AV
#define READ_A(AV, MTP, B)                                                     \
    AV[0][0] = *(const bf16x8*)((B) + aBase + (2*(MTP)+0)*2048 + k0o);         \
    AV[0][1] = *(const bf16x8*)((B) + aBase + (2*(MTP)+0)*2048 + k1o);         \
    AV[1][0] = *(const bf16x8*)((B) + aBase + (2*(MTP)+1)*2048 + k0o);         \
    AV[1][1] = *(const bf16x8*)((B) + aBase + (2*(MTP)+1)*2048 + k1o);

// read B-frag half NT (both matrices, both kk) from buffer B into set SS
#define READ_B_HALF(SS, NT, B)                                                 \
    Bz[SS][NT][0] = *(const bf16x8*)((B) + zBase + (NT)*2048 + k0o);           \
    Bz[SS][NT][1] = *(const bf16x8*)((B) + zBase + (NT)*2048 + k1o);           \
    Bh[SS][NT][0] = *(const bf16x8*)((B) + hBase + (NT)*2048 + k0o);           \
    Bh[SS][NT][1] = *(const bf16x8*)((B) + hBase + (NT)*2048 + k1o);

// stage one full K-tile (64 KB/block, 8 issues/wave) at K-byte-offset KO,
// A rows from PA (per-rep base), into buffer BN
#define STAGE8(PA, BN, KO)                                                     \
    gload16((PA) + (KO),          (BN) + ldsA);                                \
    gload16((PA) + (KO) + 16384,  (BN) + ldsA + 512);                          \
    gload16((PA) + (KO) + 32768,  (BN) + ldsA + 1024);                         \
    gload16((PA) + (KO) + 49152,  (BN) + ldsA + 1536);                         \
    gload16(gZ + (KO),            (BN) + ldsZ);                                \
    gload16(gZ + (KO) + 16384,    (BN) + ldsZ + 512);                          \
    gload16(gH + (KO),            (BN) + ldsH);                                \
    gload16(gH + (KO) + 16384,    (BN) + ldsH + 512);

// One K-tile, literal buffer parity S (round-2 schedule: stage t+1 at P0,
// publish with vmcnt(0) at P3 -- drain is free at 9% HBM load; frag reads
// for t+1 issued under P3's MFMA, B half1 after it to cap liveness).
// A panel comes from gAr (per-rep pointer -- the round-5 bug was using gA).
#define TILE(KT, S)                                                            \
    {                                                                          \
        const int ktv = (KT);                                                  \
        const char*     bcc = (const char*)&smem[S][0];                        \
        unsigned short* bn  = &smem[(S) ^ 1][0];                               \
        const char*     bnc = (const char*)bn;                                 \
        const bool pf = (ktv + 1 < NKT);                                       \
        const size_t ko = (size_t)(ktv + 1) * 128;                             \
        /* P0 */                                                               \
        if (pf) { STAGE8(gAr, bn, ko) }                                        \
        READ_A(A1, 1, bcc)                                                     \
        PRIO1; MFMA_PAIR(0, A0, S) PRIO0; SBAR;                                \
        /* P1 */                                                               \
        READ_A(A0, 2, bcc)                                                     \
        PRIO1; MFMA_PAIR(1, A1, S) PRIO0; SBAR;                                \
        /* P2 */                                                               \
        READ_A(A1, 3, bcc)                                                     \
        PRIO1; MFMA_PAIR(2, A0, S) PRIO0; SBAR;                                \
        /* P3 */                                                               \
        if (pf) {                                                              \
            asm volatile("s_waitcnt vmcnt(0)" ::: "memory");                   \
            __builtin_amdgcn_s_barrier();                                      \
            READ_B_HALF((S) ^ 1, 0, bnc)                                       \
            READ_A(A0, 0, bnc)                                                 \
        }                                                                      \
        PRIO1; MFMA_PAIR(3, A1, S) PRIO0; SBAR;                                \
        if (pf) { READ_B_HALF((S) ^ 1, 1, bnc) }                               \
    }

// Last K-tile of a rep: no publish; rep 0 pre-stages the SECOND tile's
// K-tile-0 (A panel gAr+AOFF) into buf0 at P0 so its HBM latency hides
// under TILE15's MFMA + the epilogue.
#define TILE15(FIRSTREP)                                                       \
    {                                                                          \
        const char* bcc = (const char*)&smem[1][0];                            \
        READ_A(A1, 1, bcc)                                                     \
        if (FIRSTREP) { STAGE8(gAr + AOFF, &smem[0][0], 0) }                   \
        PRIO1; MFMA_PAIR(0, A0, 1) PRIO0; SBAR;                                \
        READ_A(A0, 2, bcc)                                                     \
        PRIO1; MFMA_PAIR(1, A1, 1) PRIO0; SBAR;                                \
        READ_A(A1, 3, bcc)                                                     \
        PRIO1; MFMA_PAIR(2, A0, 1) PRIO0; SBAR;                                \
        PRIO1; MFMA_PAIR(3, A1, 1) PRIO0; SBAR;                                \
    }

// ---------- pipelined dual-GEMM + activation epilogue + fused chunk carries ----------
// grid 256: each block does tiles (typ, tx) and (typ+32, tx) back-to-back --
// one resident generation, no inter-dispatch bubble, B panel re-staged L2-hot.
__global__ __launch_bounds__(512, 1) void gemm_act_8ph(
    const unsigned short* __restrict__ xb, const unsigned short* __restrict__ zb,
    const unsigned short* __restrict__ hb, const float* __restrict__ bz,
    const float* __restrict__ bh, unsigned int* __restrict__ ab,
    float* __restrict__ carryA, float* __restrict__ carryB)
{
    // per buffer (32768 shorts): A [256][64] @0, Bz [128][64] @16384, Bh @24576
    __shared__ unsigned short smem[2][32768];      // 128 KiB total

    const int tid  = threadIdx.x;
    const int wid  = tid >> 6;           // 0..7
    const int lane = tid & 63;
    const int lm   = lane & 15;
    const int q    = lane >> 4;
    const int wr   = wid >> 2;           // m-half (128 rows)
    const int wc   = wid & 3;            // n-quarter (32 cols)

    // bijective XCD swizzle: 256 blocks, 8 XCDs, 32 per XCD
    const int bid = blockIdx.x;
    const int s   = (bid & 7) * 32 + (bid >> 3);
    const int tx  = s & 7;               // 0..7
    const int typ = s >> 3;              // 0..31
    const int m0  = typ * GBM;           // rep 0 rows; rep 1 adds 8192
    const int n0  = tx * GBN;

    // ---- staging addresses (1 KB per issue = 8 rows x 128 B) ----
    // LDS dest linear (wave-uniform base + lane*16); T2 swizzle applied by
    // permuting the per-lane GLOBAL source column: slot_src = sl ^ row&7.
    const int l8   = lane >> 3;                    // row within 8-row issue
    const int sl   = lane & 7;                     // 16B slot
    const int scol = 16 * (sl ^ l8);               // pre-swizzled source byte col
    const char* gA = (const char*)xb + ((size_t)(m0 + wid * 32 + l8) * DIN) * 2 + scol;
    const char* gZ = (const char*)zb + ((size_t)(n0 + wid * 16 + l8) * DIN) * 2 + scol;
    const char* gH = (const char*)hb + ((size_t)(n0 + wid * 16 + l8) * DIN) * 2 + scol;
    const char* gAr = gA;                          // per-rep A panel (+= AOFF)
    const int ldsA = wid * 2048;                   // shorts; +j*512 per issue
    const int ldsZ = 16384 + wid * 1024;
    const int ldsH = 24576 + wid * 1024;

    // ---- swizzled read addresses ----
    const int sw  = (lm & 7) << 4;
    const int k0o = (q * 16) ^ sw;                 // kk=0 slot byte (swizzled)
    const int k1o = (64 + q * 16) ^ sw;            // kk=1
    const int aBase = (wr * 128 + lm) * 128;       // byte; +row*2048
    const int zBase = 32768 + (wc * 32 + lm) * 128;
    const int hBase = 49152 + (wc * 32 + lm) * 128;

    f32x4 accz[8][2], acch[8][2];
    bf16x8 A0[2][2], A1[2][2];            // A-frag ping-pong (one phase ahead)
    bf16x8 Bz[2][2][2], Bh[2][2][2];      // B-frag sets per tile parity

    // ---- prologue: stage rep-0 K-tile 0 into buf0, publish ----
    {
        STAGE8(gAr, &smem[0][0], 0)
        asm volatile("s_waitcnt vmcnt(0)" ::: "memory");
        __builtin_amdgcn_s_barrier();
    }

#pragma unroll 1
    for (int rep = 0; rep < 2; ++rep) {
        const char* b0c = (const char*)&smem[0][0];
#pragma unroll
        for (int mt = 0; mt < 8; ++mt)
#pragma unroll
            for (int nt = 0; nt < 2; ++nt) {
                accz[mt][nt] = (f32x4){0.f, 0.f, 0.f, 0.f};
                acch[mt][nt] = (f32x4){0.f, 0.f, 0.f, 0.f};
            }
        READ_B_HALF(0, 0, b0c)
        READ_B_HALF(0, 1, b0c)
        READ_A(A0, 0, b0c)

        for (int kt = 0; kt < 14; kt += 2) {
            TILE(kt, 0)
            TILE(kt + 1, 1)
        }
        TILE(14, 0)
        TILE15(rep == 0)

        // ---- epilogue: activations, ab pack, per-16-row chunk carries ----
        // C layout: col = lm, row = q*4 + r
        const int m0r = m0 + rep * 8192;
        const int bi  = m0r >> 12;
        const int cb0 = ((m0r & 4095) >> 4) + wr * 8;   // 8 chunks (1 per mt)

#pragma unroll
        for (int nt = 0; nt < 2; ++nt) {
            const int col = n0 + wc * 32 + nt * 16 + lm;
            const float bzv = bz[col];
            const float bhv = bh[col];
#pragma unroll
            for (int mt = 0; mt < 8; ++mt) {
                const int row0 = m0r + wr * 128 + mt * 16 + q * 4;
                float A = 1.f, B = 0.f;
#pragma unroll
                for (int r = 0; r < 4; ++r) {
                    const float kpre = accz[mt][nt][r] + bzv;
                    const float hpre = acch[mt][nt][r] + bhv;
                    const float ez   = __expf(-kpre);
                    const float zv   = 1.0f / (1.0f + ez);   // sigmoid(k)
                    const float avv  = ez * zv;              // sigmoid(-k)
                    const float g    = (hpre >= 0.f) ? (hpre + 0.5f)
                                                     : (1.0f / (1.0f + __expf(-hpre)));
                    const float bv   = zv * g;
                    ab[(size_t)(row0 + r) * HDIM + col] = pk2(avv, bv);
                    A = avv * A;                  // compose ascending t
                    B = fmaf(avv, B, bv);
                }
                // compose across q (rows q*4..q*4+3 -> full 16-row chunk)
                float A2 = __shfl_xor(A, 16, 64);
                float B2 = __shfl_xor(B, 16, 64);
                B = (q & 1) ? fmaf(A, B2, B) : fmaf(A2, B, B2);
                A = A * A2;
                A2 = __shfl_xor(A, 32, 64);
                B2 = __shfl_xor(B, 32, 64);
                B = (q & 2) ? fmaf(A, B2, B) : fmaf(A2, B, B2);
                A = A * A2;
                if (q == 0) {
                    const int cseq = cb0 + mt;
                    const size_t ci = ((size_t)(cseq * BSZ + bi)) * HDIM + col;
                    carryA[ci] = A;
                    carryB[ci] = B;
                }
            }
        }

        if (rep == 0) {   // rep-1's K-tile 0 staged during TILE15+epilogue
            asm volatile("s_waitcnt vmcnt(0)" ::: "memory");
            __builtin_amdgcn_s_barrier();
            gAr += AOFF;  // switch TILE staging to the second A panel
        }
    }
}

// ---------- Phase B: sequential scan over chunk carries (batch-32 loads) ----------
__global__ __launch_bounds__(256) void scan_phaseB(
    const float* __restrict__ h0, const float* __restrict__ carryA,
    const float* __restrict__ carryB, float* __restrict__ hin)
{
    const int h  = blockIdx.x * 256 + threadIdx.x;
    const int bi = blockIdx.y;
    const float v = h0[(size_t)bi * HDIM + h];
    float hr = (v >= 0.0f) ? (v + 0.5f) : (1.0f / (1.0f + __expf(-v)));
    for (int c0 = 0; c0 < NCH; c0 += 32) {
        float a[32], b[32];
#pragma unroll
        for (int j = 0; j < 32; ++j) {
            const size_t ci = ((size_t)(c0 + j) * BSZ + bi) * HDIM + h;
            a[j] = carryA[ci];
            b[j] = carryB[ci];
        }
#pragma unroll
        for (int j = 0; j < 32; ++j) {
            const size_t ci = ((size_t)(c0 + j) * BSZ + bi) * HDIM + h;
            hin[ci] = hr;
            hr = fmaf(a[j], hr, b[j]);
        }
    }
}

// ---------- Phase C: replay chunk with known h_in, 4 channels/thread ----------
__global__ __launch_bounds__(256) void scan_phaseC(
    const unsigned int* __restrict__ ab, const float* __restrict__ hin,
    float* __restrict__ out)
{
    const int c  = blockIdx.x;     // 0..NCH-1
    const int bi = blockIdx.y;     // 0..3
    const int h  = threadIdx.x * 4;
    size_t idx = ((size_t)bi * SEQ + (size_t)c * CL) * HDIM + h;
    const size_t ci = ((size_t)c * BSZ + bi) * HDIM + h;
    float4 hr = *(const float4*)&hin[ci];
#pragma unroll 8
    for (int t = 0; t < CL; ++t) {
        const uint4 v = *(const uint4*)&ab[idx];
        hr.x = fmaf(bf2f(v.x & 0xffffu), hr.x, bf2f(v.x >> 16));
        hr.y = fmaf(bf2f(v.y & 0xffffu), hr.y, bf2f(v.y >> 16));
        hr.z = fmaf(bf2f(v.z & 0xffffu), hr.z, bf2f(v.z >> 16));
        hr.w = fmaf(bf2f(v.w & 0xffffu), hr.w, bf2f(v.w >> 16));
        *(float4*)&out[idx] = hr;
        idx += HDIM;
    }
}

extern "C" void kernel_launch(void* const* d_in, const int* in_sizes, int n_in,
                              void* d_out, int out_size, void* d_ws, size_t ws_size,
                              hipStream_t stream)
{
    const float* x  = (const float*)d_in[0];
    const float* h0 = (const float*)d_in[1];
    const float* Wz = (const float*)d_in[2];
    const float* bz = (const float*)d_in[3];
    const float* Wh = (const float*)d_in[4];
    const float* bh = (const float*)d_in[5];
    float* out = (float*)d_out;

    // workspace (~118 MB; ws_size known >= 137 MB)
    unsigned int*   ab  = (unsigned int*)d_ws;             // NELE
    unsigned short* xbf = (unsigned short*)(ab + NELE);    // NX
    unsigned short* zbf = xbf + NX;                        // NW
    unsigned short* hbf = zbf + NW;                        // NW
    float* carryA = (float*)(hbf + NW);                    // NCH*BSZ*HDIM
    float* carryB = carryA + (size_t)NCH * BSZ * HDIM;
    float* hin    = carryB + (size_t)NCH * BSZ * HDIM;

    const int cvtBlocks = (int)((X4 + 2 * W4) / 2 / 256);  // 9216
    cvt_bf16<<<cvtBlocks, 256, 0, stream>>>(x, Wz, Wh, xbf, zbf, hbf);

    dim3 gGrid((MTOT / GBM / 2) * (HDIM / GBN));           // 32*8 = 256 blocks
    gemm_act_8ph<<<gGrid, 512, 0, stream>>>(xbf, zbf, hbf, bz, bh, ab, carryA, carryB);

    dim3 bGrid(HDIM / 256, BSZ);                           // (4, 4)
    scan_phaseB<<<bGrid, 256, 0, stream>>>(h0, carryA, carryB, hin);

    dim3 cGrid(NCH, BSZ);                                  // (256, 4)
    scan_phaseC<<<cGrid, 256, 0, stream>>>(ab, hin, out);
}

// Round 7
// 231.312 us; speedup vs baseline: 1.1284x; 1.1284x over previous
//
#include <hip/hip_runtime.h>
#include <cstddef>
#include <cstdint>

#define BSZ   4
#define SEQ   4096
#define DIN   1024
#define HDIM  1024
#define MTOT  (BSZ * SEQ)            // 16384 rows
#define NELE  ((size_t)MTOT * HDIM)
#define NX    ((size_t)MTOT * DIN)
#define NW    ((size_t)HDIM * DIN)
#define NCH   128                    // scan chunks (CL=32)
#define CL    (SEQ / NCH)

#define X4 (NX / 4)
#define W4 (NW / 4)

// GEMM tile geometry
#define GBM 256
#define GBN 128
#define GBK 64
#define NKT (DIN / GBK)              // 16 K-tiles

using bf16x8 = __attribute__((ext_vector_type(8))) __bf16;
using f32x4  = __attribute__((ext_vector_type(4))) float;

// ---------- bf16 bit helpers ----------
__device__ __forceinline__ float bf2f(unsigned int u16bits) {
    union { unsigned int i; float f; } v;
    v.i = u16bits << 16;
    return v.f;
}
__device__ __forceinline__ unsigned int pk2(float a, float b) {  // (lo=a, hi=b)
    union { float f; unsigned int i; } ua, ub; ua.f = a; ub.f = b;
    return ((ua.i + 0x8000u) >> 16) | ((ub.i + 0x8000u) & 0xffff0000u);
}

// async 16B global -> LDS (wave-uniform LDS base; HW adds lane*16)
__device__ __forceinline__ void gload16(const void* g, void* l) {
    __builtin_amdgcn_global_load_lds(
        (const __attribute__((address_space(1))) unsigned int*)g,
        (__attribute__((address_space(3))) unsigned int*)l, 16, 0, 0);
}

// ---------- fp32 -> bf16 pre-convert (x, Wz, Wh) ----------
// One float4 per thread -> one uint2 (2x2 packed bf16). All lanes contiguous
// on both load (16B) and store (8B) -- no strided half-used loads.
__global__ __launch_bounds__(256) void cvt_bf16(
    const float* __restrict__ x, const float* __restrict__ wz,
    const float* __restrict__ wh, unsigned short* __restrict__ xb,
    unsigned short* __restrict__ zb, unsigned short* __restrict__ hb)
{
    const size_t i = (size_t)blockIdx.x * 256 + threadIdx.x;   // float4 index
    const float4* s; uint2* d; size_t off;
    if (i < X4)           { s = (const float4*)x;  d = (uint2*)xb; off = i; }
    else if (i < X4 + W4) { s = (const float4*)wz; d = (uint2*)zb; off = i - X4; }
    else                  { s = (const float4*)wh; d = (uint2*)hb; off = i - X4 - W4; }
    const float4 v = s[off];
    uint2 r;
    r.x = pk2(v.x, v.y);
    r.y = pk2(v.z, v.w);
    d[off] = r;
}

// ---------- helper macros for the pipelined GEMM ----------
#define SBAR  __builtin_amdgcn_sched_barrier(0)
#define PRIO1 __builtin_amdgcn_s_setprio(1)
#define PRIO0 __builtin_amdgcn_s_setprio(0)

#define MFMA1(acc, va, vb) \
    acc = __builtin_amdgcn_mfma_f32_16x16x32_bf16(va, vb, acc, 0, 0, 0)

// 32 MFMA for mt-pair P (rows 2P,2P+1) using A-set AV and B-set S
#define MFMA_PAIR(P, AV, S)                                                    \
    _Pragma("unroll")                                                          \
    for (int i_ = 0; i_ < 2; ++i_) {                                           \
        _Pragma("unroll")                                                      \
        for (int nt_ = 0; nt_ < 2; ++nt_) {                                    \
            MFMA1(accz[2*(P)+i_][nt_], AV[i_][0], Bz[S][nt_][0]);              \
            MFMA1(acch[2*(P)+i_][nt_], AV[i_][0], Bh[S][nt_][0]);              \
            MFMA1(accz[2*(P)+i_][nt_], AV[i_][1], Bz[S][nt_][1]);              \
            MFMA1(acch[2*(P)+i_][nt_], AV[i_][1], Bh[S][nt_][1]);              \
        }                                                                      \
    }

// read A-frag pair MTP (rows 2*MTP, 2*MTP+1) from buffer B into set AV
#define READ_A(AV, MTP, B)                                                     \
    AV[0][0] = *(const bf16x8*)((B) + aBase + (2*(MTP)+0)*2048 + k0o);         \
    AV[0][1] = *(const bf16x8*)((B) + aBase + (2*(MTP)+0)*2048 + k1o);         \
    AV[1][0] = *(const bf16x8*)((B) + aBase + (2*(MTP)+1)*2048 + k0o);         \
    AV[1][1] = *(const bf16x8*)((B) + aBase + (2*(MTP)+1)*2048 + k1o);

// read B-frag half NT (both matrices, both kk) from buffer B into set SS
#define READ_B_HALF(SS, NT, B)                                                 \
    Bz[SS][NT][0] = *(const bf16x8*)((B) + zBase + (NT)*2048 + k0o);           \
    Bz[SS][NT][1] = *(const bf16x8*)((B) + zBase + (NT)*2048 + k1o);           \
    Bh[SS][NT][0] = *(const bf16x8*)((B) + hBase + (NT)*2048 + k0o);           \
    Bh[SS][NT][1] = *(const bf16x8*)((B) + hBase + (NT)*2048 + k1o);

// stage one full K-tile (64 KB/block, 8 issues/wave) at K-byte-offset KO into BN
#define STAGE8(BN, KO)                                                         \
    gload16(gA + (KO),          (BN) + ldsA);                                  \
    gload16(gA + (KO) + 16384,  (BN) + ldsA + 512);                            \
    gload16(gA + (KO) + 32768,  (BN) + ldsA + 1024);                           \
    gload16(gA + (KO) + 49152,  (BN) + ldsA + 1536);                           \
    gload16(gZ + (KO),          (BN) + ldsZ);                                  \
    gload16(gZ + (KO) + 16384,  (BN) + ldsZ + 512);                            \
    gload16(gH + (KO),          (BN) + ldsH);                                  \
    gload16(gH + (KO) + 16384,  (BN) + ldsH + 512);

// One K-tile, literal buffer parity S. ONE barrier per tile (publish at P3).
// Round-2 schedule (best measured): stage t+1 at P0; publish with vmcnt(0)
// at P3 (drain is free at ~9% HBM load); t+1's P0 frags read under P3's MFMA.
#define TILE(KT, S)                                                            \
    {                                                                          \
        const int ktv = (KT);                                                  \
        const char*     bcc = (const char*)&smem[S][0];                        \
        unsigned short* bn  = &smem[(S) ^ 1][0];                               \
        const char*     bnc = (const char*)bn;                                 \
        const bool pf = (ktv + 1 < NKT);                                       \
        const size_t ko = (size_t)(ktv + 1) * 128;                             \
        /* P0 */                                                               \
        if (pf) { STAGE8(bn, ko) }                                             \
        READ_A(A1, 1, bcc)                                                     \
        PRIO1; MFMA_PAIR(0, A0, S) PRIO0; SBAR;                                \
        /* P1 */                                                               \
        READ_A(A0, 2, bcc)                                                     \
        PRIO1; MFMA_PAIR(1, A1, S) PRIO0; SBAR;                                \
        /* P2 */                                                               \
        READ_A(A1, 3, bcc)                                                     \
        PRIO1; MFMA_PAIR(2, A0, S) PRIO0; SBAR;                                \
        /* P3: publish next buffer, prefetch its P0 frags under MFMA */        \
        if (pf) {                                                              \
            asm volatile("s_waitcnt vmcnt(0)" ::: "memory");                   \
            __builtin_amdgcn_s_barrier();                                      \
            READ_B_HALF((S) ^ 1, 0, bnc)                                       \
            READ_A(A0, 0, bnc)                                                 \
        }                                                                      \
        PRIO1; MFMA_PAIR(3, A1, S) PRIO0; SBAR;                                \
        if (pf) { READ_B_HALF((S) ^ 1, 1, bnc) }                               \
    }

// ---------- pipelined dual-GEMM + activation epilogue + fused chunk carries ----------
__global__ __launch_bounds__(512, 1) void gemm_act_8ph(
    const unsigned short* __restrict__ xb, const unsigned short* __restrict__ zb,
    const unsigned short* __restrict__ hb, const float* __restrict__ bz,
    const float* __restrict__ bh, unsigned int* __restrict__ ab,
    float* __restrict__ carryA, float* __restrict__ carryB)
{
    // per buffer (32768 shorts): A [256][64] @0, Bz [128][64] @16384, Bh @24576
    __shared__ unsigned short smem[2][32768];      // 128 KiB total

    const int tid  = threadIdx.x;
    const int wid  = tid >> 6;           // 0..7
    const int lane = tid & 63;
    const int lm   = lane & 15;
    const int q    = lane >> 4;
    const int wr   = wid >> 2;           // m-half (128 rows)
    const int wc   = wid & 3;            // n-quarter (32 cols)

    // bijective XCD swizzle: 512 blocks, 8 XCDs, 64 per XCD (same-ty blocks share A panel)
    const int bid = blockIdx.x;
    const int swz = (bid & 7) * 64 + (bid >> 3);
    const int ty  = swz >> 3;            // 0..63
    const int tx  = swz & 7;             // 0..7
    const int m0  = ty * GBM;
    const int n0  = tx * GBN;

    // ---- staging addresses (1 KB per issue = 8 rows x 128 B) ----
    // LDS dest linear (wave-uniform base + lane*16); T2 swizzle applied by
    // permuting the per-lane GLOBAL source column: slot_src = sl ^ row&7.
    const int l8   = lane >> 3;                    // row within 8-row issue
    const int sl   = lane & 7;                     // 16B slot
    const int scol = 16 * (sl ^ l8);               // pre-swizzled source byte col
    const char* gA = (const char*)xb + ((size_t)(m0 + wid * 32 + l8) * DIN) * 2 + scol;
    const char* gZ = (const char*)zb + ((size_t)(n0 + wid * 16 + l8) * DIN) * 2 + scol;
    const char* gH = (const char*)hb + ((size_t)(n0 + wid * 16 + l8) * DIN) * 2 + scol;
    const int ldsA = wid * 2048;                   // shorts; +j*512 per issue
    const int ldsZ = 16384 + wid * 1024;
    const int ldsH = 24576 + wid * 1024;

    // ---- swizzled read addresses ----
    const int sw  = (lm & 7) << 4;
    const int k0o = (q * 16) ^ sw;                 // kk=0 slot byte (swizzled)
    const int k1o = (64 + q * 16) ^ sw;            // kk=1
    const int aBase = (wr * 128 + lm) * 128;       // byte; +row*2048
    const int zBase = 32768 + (wc * 32 + lm) * 128;
    const int hBase = 49152 + (wc * 32 + lm) * 128;

    f32x4 accz[8][2], acch[8][2];
#pragma unroll
    for (int mt = 0; mt < 8; ++mt)
#pragma unroll
        for (int nt = 0; nt < 2; ++nt) {
            accz[mt][nt] = (f32x4){0.f, 0.f, 0.f, 0.f};
            acch[mt][nt] = (f32x4){0.f, 0.f, 0.f, 0.f};
        }

    bf16x8 A0[2][2], A1[2][2];            // A-frag ping-pong (one phase ahead)
    bf16x8 Bz[2][2][2], Bh[2][2][2];      // B-frag sets per tile parity

    // ---- prologue: stage K-tile 0 into buf 0, publish, load its frags ----
    {
        unsigned short* b0 = &smem[0][0];
        const char*     b0c = (const char*)b0;
        STAGE8(b0, 0)
        asm volatile("s_waitcnt vmcnt(0)" ::: "memory");
        __builtin_amdgcn_s_barrier();
        READ_B_HALF(0, 0, b0c)
        READ_B_HALF(0, 1, b0c)
        READ_A(A0, 0, b0c)
    }

    for (int kt = 0; kt < NKT; kt += 2) {
        TILE(kt, 0)
        TILE(kt + 1, 1)
    }

    // ---- epilogue: activations, ab pack, fused per-32-row chunk carries ----
    // C layout: col = lm, row = q*4 + r
    const int bi  = m0 >> 12;
    const int cb0 = ((m0 & 4095) >> 5) + wr * 4;   // 4 chunks (8 mt = 4 pairs) per wave

#pragma unroll
    for (int nt = 0; nt < 2; ++nt) {
        const int col = n0 + wc * 32 + nt * 16 + lm;
        const float bzv = bz[col];
        const float bhv = bh[col];
#pragma unroll
        for (int pr = 0; pr < 4; ++pr) {
            float CA = 1.f, CB = 0.f;
#pragma unroll
            for (int mi = 0; mi < 2; ++mi) {
                const int mt   = pr * 2 + mi;
                const int row0 = m0 + wr * 128 + mt * 16 + q * 4;
                float A = 1.f, B = 0.f;
#pragma unroll
                for (int r = 0; r < 4; ++r) {
                    const float kpre = accz[mt][nt][r] + bzv;
                    const float hpre = acch[mt][nt][r] + bhv;
                    const float ez   = __expf(-kpre);
                    const float zv   = 1.0f / (1.0f + ez);   // sigmoid(k)
                    const float avv  = ez * zv;              // sigmoid(-k)
                    const float g    = (hpre >= 0.f) ? (hpre + 0.5f)
                                                     : (1.0f / (1.0f + __expf(-hpre)));
                    const float bv   = zv * g;
                    ab[(size_t)(row0 + r) * HDIM + col] = pk2(avv, bv);
                    A = avv * A;                  // compose ascending t
                    B = fmaf(avv, B, bv);
                }
                // compose across q (rows q*4..q*4+3 -> full 16-row segment)
                float A2 = __shfl_xor(A, 16, 64);
                float B2 = __shfl_xor(B, 16, 64);
                B = (q & 1) ? fmaf(A, B2, B) : fmaf(A2, B, B2);
                A = A * A2;
                A2 = __shfl_xor(A, 32, 64);
                B2 = __shfl_xor(B, 32, 64);
                B = (q & 2) ? fmaf(A, B2, B) : fmaf(A2, B, B2);
                A = A * A2;
                // chunk compose across mt (ascending)
                CB = fmaf(A, CB, B);
                CA = A * CA;
            }
            if (q == 0) {
                const int cseq = cb0 + pr;
                const size_t ci = ((size_t)(cseq * BSZ + bi)) * HDIM + col;
                carryA[ci] = CA;
                carryB[ci] = CB;
            }
        }
    }
}

// ---------- Phase B: sequential scan over chunk carries (batched prefetch) ----------
__global__ __launch_bounds__(256) void scan_phaseB(
    const float* __restrict__ h0, const float* __restrict__ carryA,
    const float* __restrict__ carryB, float* __restrict__ hin)
{
    const int h  = blockIdx.x * 256 + threadIdx.x;
    const int bi = blockIdx.y;
    const float v = h0[(size_t)bi * HDIM + h];
    float hr = (v >= 0.0f) ? (v + 0.5f) : (1.0f / (1.0f + __expf(-v)));
    for (int c0 = 0; c0 < NCH; c0 += 8) {
        float a[8], b[8];
#pragma unroll
        for (int j = 0; j < 8; ++j) {
            const size_t ci = ((size_t)(c0 + j) * BSZ + bi) * HDIM + h;
            a[j] = carryA[ci];
            b[j] = carryB[ci];
        }
#pragma unroll
        for (int j = 0; j < 8; ++j) {
            const size_t ci = ((size_t)(c0 + j) * BSZ + bi) * HDIM + h;
            hin[ci] = hr;
            hr = fmaf(a[j], hr, b[j]);
        }
    }
}

// ---------- Phase C: replay chunk with known h_in ----------
// 2 channels/thread, H split across grid.z -> 1024 blocks (4/CU) so the
// serial 32-step chain has 2x the wave-level latency hiding of the old
// 512-block layout. Explicit next-load rotation decouples load from chain.
__global__ __launch_bounds__(256) void scan_phaseC(
    const unsigned int* __restrict__ ab, const float* __restrict__ hin,
    float* __restrict__ out)
{
    const int c  = blockIdx.x;     // 0..127
    const int bi = blockIdx.y;     // 0..3
    const int h  = (blockIdx.z * 256 + threadIdx.x) * 2;
    size_t idx = ((size_t)bi * SEQ + (size_t)c * CL) * HDIM + h;
    const size_t ci = ((size_t)c * BSZ + bi) * HDIM + h;
    float2 hr = *(const float2*)&hin[ci];
    uint2 v = *(const uint2*)&ab[idx];
#pragma unroll 4
    for (int t = 0; t < CL; ++t) {
        uint2 vn;
        if (t + 1 < CL) vn = *(const uint2*)&ab[idx + HDIM];
        hr.x = fmaf(bf2f(v.x & 0xffffu), hr.x, bf2f(v.x >> 16));
        hr.y = fmaf(bf2f(v.y & 0xffffu), hr.y, bf2f(v.y >> 16));
        *(float2*)&out[idx] = hr;
        v = vn;
        idx += HDIM;
    }
}

extern "C" void kernel_launch(void* const* d_in, const int* in_sizes, int n_in,
                              void* d_out, int out_size, void* d_ws, size_t ws_size,
                              hipStream_t stream)
{
    const float* x  = (const float*)d_in[0];
    const float* h0 = (const float*)d_in[1];
    const float* Wz = (const float*)d_in[2];
    const float* bz = (const float*)d_in[3];
    const float* Wh = (const float*)d_in[4];
    const float* bh = (const float*)d_in[5];
    float* out = (float*)d_out;

    // workspace (~111 MB; ws_size known >= 137 MB)
    unsigned int*   ab  = (unsigned int*)d_ws;             // NELE
    unsigned short* xbf = (unsigned short*)(ab + NELE);    // NX
    unsigned short* zbf = xbf + NX;                        // NW
    unsigned short* hbf = zbf + NW;                        // NW
    float* carryA = (float*)(hbf + NW);                    // NCH*BSZ*HDIM
    float* carryB = carryA + (size_t)NCH * BSZ * HDIM;
    float* hin    = carryB + (size_t)NCH * BSZ * HDIM;

    const int cvtBlocks = (int)((X4 + 2 * W4) / 256);      // 18432
    cvt_bf16<<<cvtBlocks, 256, 0, stream>>>(x, Wz, Wh, xbf, zbf, hbf);

    dim3 gGrid((MTOT / GBM) * (HDIM / GBN));               // 64*8 = 512 blocks
    gemm_act_8ph<<<gGrid, 512, 0, stream>>>(xbf, zbf, hbf, bz, bh, ab, carryA, carryB);

    dim3 bGrid(HDIM / 256, BSZ);                           // (4, 4)
    scan_phaseB<<<bGrid, 256, 0, stream>>>(h0, carryA, carryB, hin);

    dim3 cGrid(NCH, BSZ, 2);                               // (128, 4, 2) = 1024 blocks
    scan_phaseC<<<cGrid, 256, 0, stream>>>(ab, hin, out);
}